// Round 1
// 408.776 us; speedup vs baseline: 1.0215x; 1.0215x over previous
//
#include <hip/hip_runtime.h>

// ViewMorphing forward — MI355X (gfx950)
// out[0 .. 3*N*HW-1] = warped+masked image sum, out[3*N*HW] = oob loss scalar.
//
// v2: latency-bound -> restructure for MLP + scalar-base addressing.
//  - n, hw derived from blockIdx (block-uniform image base => saddr loads)
//  - 4 pixels/thread, exact grid, float4 stream loads/stores
//  - bilinear taps as adjacent pairs (dwordx2-mergeable), imm-folded offsets
//  - exact-integer-coordinate doubling of the reference (ceil==floor case)
//    reproduced via per-pixel weight scale

constexpr int D    = 512;
constexpr int HW   = D * D;            // 262144 = 2^18
constexpr int NB   = 32;
constexpr int NPIX = NB * HW;          // 8,388,608
// loss scale: 0.01 / (N*2*HW) / (D*D)
constexpr float LOSS_SCALE = (float)(0.01 / (2.0 * (double)NPIX * (double)HW));

typedef float f4 __attribute__((ext_vector_type(4)));

// Bilinear 3-channel sample from image base p (block-uniform -> SGPR base).
// Accumulates oob penalty; wscale carries the reference's weight-doubling
// factor for exactly-integral coordinates (where ceil==floor).
__device__ __forceinline__ float3 sample3(const float* __restrict__ p,
                                          float q0o, float q1o,
                                          float& oob, float& wscale)
{
    const float hi = 510.999f;                  // D - 1.001
    float q0 = fminf(fmaxf(q0o, 0.001f), hi);
    float q1 = fminf(fmaxf(q1o, 0.001f), hi);
    float d0 = q0o - q0, d1 = q1o - q1;
    oob = fmaf(d0, d0, oob);
    oob = fmaf(d1, d1, oob);

    float fx = floorf(q0), fy = floorf(q1);
    float ax = q0 - fx,    ay = q1 - fy;        // in [0,1)
    // reference: wfx=1-ax, wcx(ceil)=ax when ceil>floor; when q integral the
    // two taps coincide and weights sum to 2 -> fold into wscale.
    float sc = ((ax == 0.0f) ? 2.0f : 1.0f) * ((ay == 0.0f) ? 2.0f : 1.0f);
    wscale = sc;

    // ind = y + D*x ; taps at (fx,fy),(fx,fy+1),(fx+1,fy),(fx+1,fy+1)
    // q0<=510.999 -> fx+1 <= 511: always in bounds.
    int off = (int)fy + (((int)fx) << 9);

    float r[3];
    #pragma unroll
    for (int c = 0; c < 3; ++c) {
        const float* pc = p + c * HW;           // uniform + uniform: stays SGPR
        float v00 = pc[off];
        float v01 = pc[off + 1];
        float v10 = pc[off + 512];
        float v11 = pc[off + 513];
        float top = fmaf(ay, v01 - v00, v00);
        float bot = fmaf(ay, v11 - v10, v10);
        r[c] = fmaf(ax, bot - top, top);
    }
    return make_float3(r[0], r[1], r[2]);
}

__global__ void __launch_bounds__(256)
vm_fwd(const float* __restrict__ im1, const float* __restrict__ im2,
       const float* __restrict__ C,   const float* __restrict__ M1,
       const float* __restrict__ M2,  float* __restrict__ out)
{
    // 1024 consecutive pixels per block -> 256 blocks per batch image,
    // so n and all image bases are block-uniform (scalar).
    const int b  = blockIdx.x;
    const int n  = b >> 8;
    const int hw = ((b & 255) << 10) | (threadIdx.x << 2);

    const float qx  = (float)(hw >> 9);         // row (same for all 4 px)
    const float qy0 = (float)(hw & 511);        // first col

    const float* Cn = C   + (size_t)n * 2 * HW;
    const float* Mp = M1  + (size_t)n * HW;
    const float* Mq = M2  + (size_t)n * HW;
    const float* p1 = im1 + (size_t)n * 3 * HW;
    const float* p2 = im2 + (size_t)n * 3 * HW;

    f4 c0 = *(const f4*)(Cn + hw);
    f4 c1 = *(const f4*)(Cn + HW + hw);
    f4 m1 = *(const f4*)(Mp + hw);
    f4 m2 = *(const f4*)(Mq + hw);

    float oob = 0.0f;
    float o0a[4], o1a[4], o2a[4];

    #pragma unroll
    for (int j = 0; j < 4; ++j) {
        float qyj = qy0 + (float)j;
        float sA, sB;
        float3 av = sample3(p1, qx + c0[j], qyj + c1[j], oob, sA);
        float3 bv = sample3(p2, qx - c0[j], qyj - c1[j], oob, sB);
        float w1 = m1[j] * sA;
        float w2 = m2[j] * sB;
        o0a[j] = fmaf(av.x, w1, bv.x * w2);
        o1a[j] = fmaf(av.y, w1, bv.y * w2);
        o2a[j] = fmaf(av.z, w1, bv.z * w2);
    }

    f4 o0 = {o0a[0], o0a[1], o0a[2], o0a[3]};
    f4 o1 = {o1a[0], o1a[1], o1a[2], o1a[3]};
    f4 o2 = {o2a[0], o2a[1], o2a[2], o2a[3]};

    size_t obase = (size_t)n * 3 * HW + hw;
    // streaming outputs: never re-read -> keep L2 for the gather taps
    __builtin_nontemporal_store(o0, (f4*)(out + obase));
    __builtin_nontemporal_store(o1, (f4*)(out + obase + HW));
    __builtin_nontemporal_store(o2, (f4*)(out + obase + 2 * HW));

    // block-level reduction of oob, then one atomic per block
    #pragma unroll
    for (int off = 32; off > 0; off >>= 1)
        oob += __shfl_down(oob, off, 64);

    __shared__ float wave_sums[4];   // 256 threads / wave64
    int lane = threadIdx.x & 63;
    int wave = threadIdx.x >> 6;
    if (lane == 0) wave_sums[wave] = oob;
    __syncthreads();
    if (threadIdx.x == 0) {
        float s = wave_sums[0] + wave_sums[1] + wave_sums[2] + wave_sums[3];
        atomicAdd(out + (size_t)3 * NPIX, s * LOSS_SCALE);
    }
}

extern "C" void kernel_launch(void* const* d_in, const int* in_sizes, int n_in,
                              void* d_out, int out_size, void* d_ws, size_t ws_size,
                              hipStream_t stream) {
    const float* im1 = (const float*)d_in[0];
    const float* im2 = (const float*)d_in[1];
    const float* C   = (const float*)d_in[2];
    const float* M1  = (const float*)d_in[3];
    const float* M2  = (const float*)d_in[4];
    float* out = (float*)d_out;

    // zero the loss scalar (harness poisons d_out with 0xAA before every launch)
    hipMemsetAsync(out + (size_t)3 * NPIX, 0, sizeof(float), stream);

    // NPIX / (256 threads * 4 px) = 8192 blocks, exact cover
    vm_fwd<<<8192, 256, 0, stream>>>(im1, im2, C, M1, M2, out);
}

// Round 3
// 404.602 us; speedup vs baseline: 1.0320x; 1.0103x over previous
//
#include <hip/hip_runtime.h>

// ViewMorphing forward — MI355X (gfx950)
// out[0 .. 3*N*HW-1] = warped+masked image sum, out[3*N*HW] = oob loss scalar.
//
// v3 (resubmit — R2 bench failed on container acquisition, kernel never ran):
//  - XCD-aware slab swizzle: blockIdx round-robins XCDs (b&7); remap so each
//    XCD owns a contiguous 1/8 of the pixel space (= 4 whole images). Halo
//    rows of the bilinear gather are then reused inside ONE XCD's L2 instead
//    of being fetched into 3-4 non-coherent L2s.
//  - nontemporal loads for C/M1/M2 (pure streams) -> don't evict tap lines.
//  - keeps v2 structure: saddr image bases, 4 px/thread, f4 NT stores.

constexpr int D    = 512;
constexpr int HW   = D * D;            // 262144 = 2^18
constexpr int NB   = 32;
constexpr int NPIX = NB * HW;          // 8,388,608
// loss scale: 0.01 / (N*2*HW) / (D*D)
constexpr float LOSS_SCALE = (float)(0.01 / (2.0 * (double)NPIX * (double)HW));

typedef float f4 __attribute__((ext_vector_type(4)));

// Bilinear 3-channel sample from image base p (block-uniform -> SGPR base).
// Accumulates oob penalty; wscale carries the reference's weight-doubling
// factor for exactly-integral coordinates (where ceil==floor).
__device__ __forceinline__ float3 sample3(const float* __restrict__ p,
                                          float q0o, float q1o,
                                          float& oob, float& wscale)
{
    const float hi = 510.999f;                  // D - 1.001
    float q0 = fminf(fmaxf(q0o, 0.001f), hi);
    float q1 = fminf(fmaxf(q1o, 0.001f), hi);
    float d0 = q0o - q0, d1 = q1o - q1;
    oob = fmaf(d0, d0, oob);
    oob = fmaf(d1, d1, oob);

    float fx = floorf(q0), fy = floorf(q1);
    float ax = q0 - fx,    ay = q1 - fy;        // in [0,1)
    // reference: when coord exactly integral, floor- and ceil-taps coincide
    // and their weights sum to 2 -> fold into wscale.
    float sc = ((ax == 0.0f) ? 2.0f : 1.0f) * ((ay == 0.0f) ? 2.0f : 1.0f);
    wscale = sc;

    // ind = y + D*x ; taps at (fx,fy),(fx,fy+1),(fx+1,fy),(fx+1,fy+1)
    // q0<=510.999 -> fx+1 <= 511: always in bounds.
    int off = (int)fy + (((int)fx) << 9);

    float r[3];
    #pragma unroll
    for (int c = 0; c < 3; ++c) {
        const float* pc = p + c * HW;           // uniform + uniform: stays SGPR
        float v00 = pc[off];
        float v01 = pc[off + 1];
        float v10 = pc[off + 512];
        float v11 = pc[off + 513];
        float top = fmaf(ay, v01 - v00, v00);
        float bot = fmaf(ay, v11 - v10, v10);
        r[c] = fmaf(ax, bot - top, top);
    }
    return make_float3(r[0], r[1], r[2]);
}

__global__ void __launch_bounds__(256)
vm_fwd(const float* __restrict__ im1, const float* __restrict__ im2,
       const float* __restrict__ C,   const float* __restrict__ M1,
       const float* __restrict__ M2,  float* __restrict__ out)
{
    // XCD slab swizzle: 8192 blocks, consecutive blockIdx round-robin the
    // 8 XCDs -> give XCD x the contiguous slab of blocks [x*1024, (x+1)*1024)
    // = 4 complete images. Halo reuse then stays within one XCD's L2.
    // Bijective: 8192 = 8 * 1024 exactly.
    const int b    = blockIdx.x;
    const int slab = ((b & 7) << 10) | (b >> 3);

    // 1024 consecutive pixels per slab-block -> 256 slab-blocks per image,
    // so n and all image bases are block-uniform (scalar).
    const int n  = slab >> 8;
    const int hw = ((slab & 255) << 10) | (threadIdx.x << 2);

    const float qx  = (float)(hw >> 9);         // row (same for all 4 px)
    const float qy0 = (float)(hw & 511);        // first col

    const float* Cn = C   + (size_t)n * 2 * HW;
    const float* Mp = M1  + (size_t)n * HW;
    const float* Mq = M2  + (size_t)n * HW;
    const float* p1 = im1 + (size_t)n * 3 * HW;
    const float* p2 = im2 + (size_t)n * 3 * HW;

    // pure streams, never re-read: nontemporal so they don't evict tap lines
    f4 c0 = __builtin_nontemporal_load((const f4*)(Cn + hw));
    f4 c1 = __builtin_nontemporal_load((const f4*)(Cn + HW + hw));
    f4 m1 = __builtin_nontemporal_load((const f4*)(Mp + hw));
    f4 m2 = __builtin_nontemporal_load((const f4*)(Mq + hw));

    float oob = 0.0f;
    float o0a[4], o1a[4], o2a[4];

    #pragma unroll
    for (int j = 0; j < 4; ++j) {
        float qyj = qy0 + (float)j;
        float sA, sB;
        float3 av = sample3(p1, qx + c0[j], qyj + c1[j], oob, sA);
        float3 bv = sample3(p2, qx - c0[j], qyj - c1[j], oob, sB);
        float w1 = m1[j] * sA;
        float w2 = m2[j] * sB;
        o0a[j] = fmaf(av.x, w1, bv.x * w2);
        o1a[j] = fmaf(av.y, w1, bv.y * w2);
        o2a[j] = fmaf(av.z, w1, bv.z * w2);
    }

    f4 o0 = {o0a[0], o0a[1], o0a[2], o0a[3]};
    f4 o1 = {o1a[0], o1a[1], o1a[2], o1a[3]};
    f4 o2 = {o2a[0], o2a[1], o2a[2], o2a[3]};

    size_t obase = (size_t)n * 3 * HW + hw;
    // streaming outputs: never re-read -> keep L2 for the gather taps
    __builtin_nontemporal_store(o0, (f4*)(out + obase));
    __builtin_nontemporal_store(o1, (f4*)(out + obase + HW));
    __builtin_nontemporal_store(o2, (f4*)(out + obase + 2 * HW));

    // block-level reduction of oob, then one atomic per block
    #pragma unroll
    for (int off = 32; off > 0; off >>= 1)
        oob += __shfl_down(oob, off, 64);

    __shared__ float wave_sums[4];   // 256 threads / wave64
    int lane = threadIdx.x & 63;
    int wave = threadIdx.x >> 6;
    if (lane == 0) wave_sums[wave] = oob;
    __syncthreads();
    if (threadIdx.x == 0) {
        float s = wave_sums[0] + wave_sums[1] + wave_sums[2] + wave_sums[3];
        atomicAdd(out + (size_t)3 * NPIX, s * LOSS_SCALE);
    }
}

extern "C" void kernel_launch(void* const* d_in, const int* in_sizes, int n_in,
                              void* d_out, int out_size, void* d_ws, size_t ws_size,
                              hipStream_t stream) {
    const float* im1 = (const float*)d_in[0];
    const float* im2 = (const float*)d_in[1];
    const float* C   = (const float*)d_in[2];
    const float* M1  = (const float*)d_in[3];
    const float* M2  = (const float*)d_in[4];
    float* out = (float*)d_out;

    // zero the loss scalar (harness poisons d_out with 0xAA before every launch)
    hipMemsetAsync(out + (size_t)3 * NPIX, 0, sizeof(float), stream);

    // NPIX / (256 threads * 4 px) = 8192 blocks, exact cover
    vm_fwd<<<8192, 256, 0, stream>>>(im1, im2, C, M1, M2, out);
}